// Round 15
// baseline (182.889 us; speedup 1.0000x reference)
//
#include <hip/hip_runtime.h>
#include <hip/hip_bf16.h>

#define D 64
#define RB 512           // rows per coarse bucket (b = row>>9)
#define RB_SHIFT 9
#define COL_BITS 18      // n_total = 150001 < 2^18; row_local in bits 18..26
#define COL_MASK 0x3FFFF
#define CHUNK 4096       // edges per partition block (489 blocks)
#define FT 512           // threads for hist/fill kernels
#define NBINS 64         // degree bins (pad/4)

// bf16 helpers (round-to-nearest-even; bf16->f32 exact)
__device__ __forceinline__ unsigned f2bf(float f) {
    unsigned u = __float_as_uint(f);
    u += 0x7fff + ((u >> 16) & 1);
    return u >> 16;
}
__device__ __forceinline__ float bf_lo(unsigned w) {
    return __uint_as_float(w << 16);
}
__device__ __forceinline__ float bf_hi(unsigned w) {
    return __uint_as_float(w & 0xffff0000u);
}

// ---------------------------------------------------------------------------
// FUSED: per-chunk bucket histogram + bf16 table conversion slice + zero-init
// of cursors/degree-bins/output (block 0 only; later kernels see the writes).
__global__ void convhist_kernel(const float* __restrict__ user_emb,
                                const float* __restrict__ item_emb,
                                unsigned short* __restrict__ tbl,
                                int n_user_rows, int n_total,
                                const int* __restrict__ row,
                                int* __restrict__ hist, int n_edges, int nb,
                                int* __restrict__ cursor, int* __restrict__ dbin,
                                float* __restrict__ out) {
    __shared__ int h[RB];
    int blk = blockIdx.x;
    if (blk == 0) {
        if (threadIdx.x < 2) cursor[threadIdx.x] = 0;
        if (threadIdx.x < NBINS) dbin[threadIdx.x] = 0;
        if (threadIdx.x == 0) out[0] = 0.0f;
    }
    for (int i = threadIdx.x; i < nb; i += FT) h[i] = 0;
    __syncthreads();
    int s = blk * CHUNK;
    int e = min(s + CHUNK, n_edges);
    for (int k = s + threadIdx.x; k < e; k += FT)
        atomicAdd(&h[row[k] >> RB_SHIFT], 1);
    __syncthreads();
    for (int i = threadIdx.x; i < nb; i += FT)
        hist[blk * nb + i] = h[i];   // coalesced row write
    // conversion slice
    size_t t = (size_t)blk * FT + threadIdx.x;
    size_t total4 = (size_t)n_total * (D / 4);
    size_t user4 = (size_t)n_user_rows * (D / 4);
    size_t stride = (size_t)gridDim.x * FT;
    for (size_t i = t; i < total4; i += stride) {
        float4 v = (i < user4) ? reinterpret_cast<const float4*>(user_emb)[i]
                               : reinterpret_cast<const float4*>(item_emb)[i - user4];
        uint2 o;
        o.x = f2bf(v.x) | (f2bf(v.y) << 16);
        o.y = f2bf(v.z) | (f2bf(v.w) << 16);
        reinterpret_cast<uint2*>(tbl)[i] = o;
    }
}

// ---------------------------------------------------------------------------
// FUSED col_sum + scan + col_scan: ONE WAVE per bucket; atomic span alloc.
__global__ void col_alloc_kernel(int* __restrict__ hist,
                                 int* __restrict__ cstart, int* __restrict__ cend,
                                 int* __restrict__ cursor, int nb, int nblk) {
    int w = (blockIdx.x * blockDim.x + threadIdx.x) >> 6;
    int lane = threadIdx.x & 63;
    if (w >= nb) return;
    int ssum = 0;
    for (int blk = lane; blk < nblk; blk += 64)
        ssum += hist[blk * nb + w];
    for (int off = 32; off > 0; off >>= 1)
        ssum += __shfl_down(ssum, off, 64);
    int base = 0;
    if (lane == 0) base = atomicAdd(cursor, ssum);
    base = __shfl(base, 0, 64);
    int total = __shfl(ssum, 0, 64);
    if (lane == 0) { cstart[w] = base; cend[w] = base + total; }
    int run = base;
    for (int b0 = 0; b0 < nblk; b0 += 64) {
        int blk = b0 + lane;
        int v = (blk < nblk) ? hist[blk * nb + w] : 0;
        int inc = v;
#pragma unroll
        for (int off = 1; off < 64; off <<= 1) {
            int t = __shfl_up(inc, off, 64);
            if (lane >= off) inc += t;
        }
        if (blk < nblk) hist[blk * nb + w] = run + (inc - v);
        run += __shfl(inc, 63, 64);   // chunk total
    }
}

// ---------------------------------------------------------------------------
// Pass C: rank via block-private LDS cursors, write to exact positions
__global__ void fill_exact_kernel(const int* __restrict__ row, const int* __restrict__ col,
                                  const float* __restrict__ val, const int* __restrict__ hist,
                                  int2* __restrict__ stage, int n_edges, int nb) {
    __shared__ int cur[RB];
    int blk = blockIdx.x;
    for (int i = threadIdx.x; i < nb; i += FT)
        cur[i] = hist[blk * nb + i];   // coalesced row read
    __syncthreads();
    int s = blk * CHUNK;
    int e = min(s + CHUNK, n_edges);
    for (int k = s + threadIdx.x; k < e; k += FT) {
        int r = row[k];
        int b = r >> RB_SHIFT;
        int pos = atomicAdd(&cur[b], 1);
        stage[pos] = make_int2(col[k] | ((r & (RB - 1)) << COL_BITS), __float_as_int(val[k]));
    }
}

// ---------------------------------------------------------------------------
// FUSED bucket finalize: row histogram -> padded scan -> atomic span alloc ->
// per-row {start,end} -> pad fill -> row-sorted scatter -> degree-bin counts.
__global__ void bucket_pad_kernel(const int* __restrict__ cstart,
                                  const int* __restrict__ cend,
                                  const int2* __restrict__ stage,
                                  int2* __restrict__ offs,
                                  int2* __restrict__ pairs,
                                  int* __restrict__ cursor,
                                  int* __restrict__ dbin, int n_total) {
    __shared__ int sc[RB];
    __shared__ int cur[RB];
    __shared__ int h2[NBINS];
    __shared__ int pbase_s;
    int b = blockIdx.x;
    int tid = threadIdx.x;
    int s = cstart[b], e = cend[b];
    sc[tid] = 0;
    if (tid < NBINS) h2[tid] = 0;
    __syncthreads();
    for (int k = s + tid; k < e; k += RB)
        atomicAdd(&sc[stage[k].x >> COL_BITS], 1);
    __syncthreads();
    int cnt = sc[tid];
    int pad = (cnt + 3) & ~3;
    __syncthreads();
    sc[tid] = pad;
    __syncthreads();
    for (int off = 1; off < RB; off <<= 1) {
        int v = (tid >= off) ? sc[tid - off] : 0;
        __syncthreads();
        sc[tid] += v;
        __syncthreads();
    }
    if (tid == RB - 1) pbase_s = atomicAdd(cursor, sc[RB - 1]);
    __syncthreads();
    int start = pbase_s + sc[tid] - pad;   // exclusive padded prefix
    int r = b * RB + tid;
    if (r < n_total) {
        offs[r] = make_int2(start, start + pad);
        atomicAdd(&h2[min(pad >> 2, NBINS - 1)], 1);
    }
    cur[tid] = start;
    for (int q = start + cnt; q < start + pad; ++q)
        pairs[q] = make_int2(0, 0);   // col 0, weight 0.0f
    __syncthreads();
    if (tid < NBINS && h2[tid] > 0) atomicAdd(&dbin[tid], h2[tid]);
    for (int k = s + tid; k < e; k += RB) {
        int2 p = stage[k];
        int rl = p.x >> COL_BITS;
        int pos = atomicAdd(&cur[rl], 1);
        pairs[pos] = make_int2(p.x & COL_MASK, p.y);
    }
}

// ---------------------------------------------------------------------------
// one wave: exclusive scan of 64 degree bins -> dcur
__global__ void scan_bins_kernel(const int* __restrict__ dbin, int* __restrict__ dcur) {
    int lane = threadIdx.x;   // 64 threads
    int v = dbin[lane];
    int inc = v;
#pragma unroll
    for (int off = 1; off < 64; off <<= 1) {
        int t = __shfl_up(inc, off, 64);
        if (lane >= off) inc += t;
    }
    dcur[lane] = inc - v;
}

// build degree-sorted row permutation (block-aggregated bin atomics)
__global__ void perm_fill_kernel(const int2* __restrict__ offs,
                                 int* __restrict__ dcur, int* __restrict__ perm,
                                 int n_total) {
    __shared__ int h[NBINS];
    __shared__ int base[NBINS];
    int tid = threadIdx.x;
    int r = blockIdx.x * 256 + tid;
    if (tid < NBINS) h[tid] = 0;
    __syncthreads();
    int bin = -1;
    if (r < n_total) {
        int2 oo = offs[r];
        bin = min((oo.y - oo.x) >> 2, NBINS - 1);
        atomicAdd(&h[bin], 1);
    }
    __syncthreads();
    if (tid < NBINS && h[tid] > 0) base[tid] = atomicAdd(&dcur[tid], h[tid]);
    __syncthreads();
    if (tid < NBINS) h[tid] = 0;
    __syncthreads();
    if (r < n_total) {
        int lpos = atomicAdd(&h[bin], 1);
        perm[base[bin] + lpos] = r;
    }
}

// ---------------------------------------------------------------------------
// gather spmm (bf16 src/dst, f32 accum): ONE 8-LANE GROUP PER ROW, rows taken
// in degree-sorted order via perm -> no intra-wave divergence. Tail-free.
__global__ void spmm_gather_kernel(const int* __restrict__ perm,
                                   const int2* __restrict__ offs,
                                   const int2* __restrict__ pairs,
                                   const unsigned short* __restrict__ src,
                                   unsigned short* __restrict__ dst, int n_total) {
    int t = blockIdx.x * blockDim.x + threadIdx.x;
    int g = t >> 3;          // group id (degree-sorted)
    int sub = t & 7;         // 16 B slice of the row
    if (g >= n_total) return;
    int r = perm[g];
    int2 oo = offs[r];
    int k = oo.x;
    int end = oo.y;
    const uint4* s4 = reinterpret_cast<const uint4*>(src);
    float a0 = 0.f, a1 = 0.f, a2 = 0.f, a3 = 0.f,
          a4 = 0.f, a5 = 0.f, a6 = 0.f, a7 = 0.f;
    for (; k + 8 <= end; k += 8) {
        int2 p[8];
        uint4 rr[8];
#pragma unroll
        for (int j = 0; j < 8; ++j) p[j] = pairs[k + j];
#pragma unroll
        for (int j = 0; j < 8; ++j) rr[j] = s4[(size_t)p[j].x * 8 + sub];
#pragma unroll
        for (int j = 0; j < 8; ++j) {
            float w = __int_as_float(p[j].y);
            a0 += w * bf_lo(rr[j].x); a1 += w * bf_hi(rr[j].x);
            a2 += w * bf_lo(rr[j].y); a3 += w * bf_hi(rr[j].y);
            a4 += w * bf_lo(rr[j].z); a5 += w * bf_hi(rr[j].z);
            a6 += w * bf_lo(rr[j].w); a7 += w * bf_hi(rr[j].w);
        }
    }
    if (k < end) {   // exactly 4 remain (padded)
        int2 p[4];
        uint4 rr[4];
#pragma unroll
        for (int j = 0; j < 4; ++j) p[j] = pairs[k + j];
#pragma unroll
        for (int j = 0; j < 4; ++j) rr[j] = s4[(size_t)p[j].x * 8 + sub];
#pragma unroll
        for (int j = 0; j < 4; ++j) {
            float w = __int_as_float(p[j].y);
            a0 += w * bf_lo(rr[j].x); a1 += w * bf_hi(rr[j].x);
            a2 += w * bf_lo(rr[j].y); a3 += w * bf_hi(rr[j].y);
            a4 += w * bf_lo(rr[j].z); a5 += w * bf_hi(rr[j].z);
            a6 += w * bf_lo(rr[j].w); a7 += w * bf_hi(rr[j].w);
        }
    }
    uint4 o;
    o.x = f2bf(a0) | (f2bf(a1) << 16);
    o.y = f2bf(a2) | (f2bf(a3) << 16);
    o.z = f2bf(a4) | (f2bf(a5) << 16);
    o.w = f2bf(a6) | (f2bf(a7) << 16);
    reinterpret_cast<uint4*>(dst + (size_t)r * D)[sub] = o;
}

// ---------------------------------------------------------------------------
// FUSED layers 0+1 batch gather: u_acc = user_emb[u] (f32) + buf0[u] (bf16)
__global__ void gather_init_acc_kernel(const int* __restrict__ users,
                                       const int* __restrict__ items,
                                       const float* __restrict__ user_emb,
                                       const float* __restrict__ item_emb,
                                       const unsigned short* __restrict__ buf,
                                       float* __restrict__ u_acc,
                                       float* __restrict__ v_acc,
                                       int batch, int n_user_rows) {
    int t = blockIdx.x * blockDim.x + threadIdx.x;
    int b = t >> 4;
    int sub = t & 15;
    if (b >= batch) return;
    int u = users[b];
    int it = items[b];
    float4 a = reinterpret_cast<const float4*>(user_emb)[(size_t)u * 16 + sub];
    float4 c = reinterpret_cast<const float4*>(item_emb)[(size_t)it * 16 + sub];
    uint2 ur = reinterpret_cast<const uint2*>(buf + (size_t)u * D)[sub];
    uint2 vr = reinterpret_cast<const uint2*>(buf + (size_t)(n_user_rows + it) * D)[sub];
    a.x += bf_lo(ur.x); a.y += bf_hi(ur.x);
    a.z += bf_lo(ur.y); a.w += bf_hi(ur.y);
    c.x += bf_lo(vr.x); c.y += bf_hi(vr.x);
    c.z += bf_lo(vr.y); c.w += bf_hi(vr.y);
    reinterpret_cast<float4*>(u_acc)[(size_t)b * 16 + sub] = a;
    reinterpret_cast<float4*>(v_acc)[(size_t)b * 16 + sub] = c;
}

// layer 2: accumulate batch rows from bf16 buf into f32 acc
__global__ void gather_acc_kernel(const int* __restrict__ users,
                                  const int* __restrict__ items,
                                  const unsigned short* __restrict__ buf,
                                  float* __restrict__ u_acc,
                                  float* __restrict__ v_acc,
                                  int batch, int n_user_rows) {
    int t = blockIdx.x * blockDim.x + threadIdx.x;
    int b = t >> 4;
    int sub = t & 15;
    if (b >= batch) return;
    uint2 ur = reinterpret_cast<const uint2*>(buf + (size_t)users[b] * D)[sub];
    uint2 vr = reinterpret_cast<const uint2*>(buf + (size_t)(n_user_rows + items[b]) * D)[sub];
    float4* up = reinterpret_cast<float4*>(u_acc) + (size_t)b * 16 + sub;
    float4* vp = reinterpret_cast<float4*>(v_acc) + (size_t)b * 16 + sub;
    float4 a = *up, c = *vp;
    a.x += bf_lo(ur.x); a.y += bf_hi(ur.x);
    a.z += bf_lo(ur.y); a.w += bf_hi(ur.y);
    c.x += bf_lo(vr.x); c.y += bf_hi(vr.x);
    c.z += bf_lo(vr.y); c.w += bf_hi(vr.y);
    *up = a;
    *vp = c;
}

// ---------------------------------------------------------------------------
// Fused final stage: per batch element, compute layer-3 ONLY for its user row
// and item row (4-unrolled, tail-free), add accumulators, dot, BCE, reduce.
__global__ void batch_l3_loss_kernel(const int* __restrict__ users,
                                     const int* __restrict__ items,
                                     const int2* __restrict__ offs,
                                     const int2* __restrict__ pairs,
                                     const unsigned short* __restrict__ buf,
                                     const float* __restrict__ u_acc,
                                     const float* __restrict__ v_acc,
                                     const float* __restrict__ labels,
                                     float* __restrict__ out,
                                     int batch, int n_user_rows) {
    int t = blockIdx.x * blockDim.x + threadIdx.x;
    int b = t >> 3;
    int sub = t & 7;
    const uint4* s4 = reinterpret_cast<const uint4*>(buf);
    float lb = 0.0f;
    if (b < batch) {
        float au[8] = {0.f}, av[8] = {0.f};
        for (int side = 0; side < 2; ++side) {
            int row = (side == 0) ? users[b] : (n_user_rows + items[b]);
            float* acc = (side == 0) ? au : av;
            int2 oo = offs[row];
            for (int k = oo.x; k + 4 <= oo.y; k += 4) {
                int2 p[4];
                uint4 rr[4];
#pragma unroll
                for (int j = 0; j < 4; ++j) p[j] = pairs[k + j];
#pragma unroll
                for (int j = 0; j < 4; ++j) rr[j] = s4[(size_t)p[j].x * 8 + sub];
#pragma unroll
                for (int j = 0; j < 4; ++j) {
                    float w = __int_as_float(p[j].y);
                    acc[0] += w * bf_lo(rr[j].x); acc[1] += w * bf_hi(rr[j].x);
                    acc[2] += w * bf_lo(rr[j].y); acc[3] += w * bf_hi(rr[j].y);
                    acc[4] += w * bf_lo(rr[j].z); acc[5] += w * bf_hi(rr[j].z);
                    acc[6] += w * bf_lo(rr[j].w); acc[7] += w * bf_hi(rr[j].w);
                }
            }
        }
        const float4* ua = reinterpret_cast<const float4*>(u_acc + (size_t)b * D);
        const float4* va = reinterpret_cast<const float4*>(v_acc + (size_t)b * D);
        float4 u0 = ua[sub * 2], u1 = ua[sub * 2 + 1];
        float4 v0 = va[sub * 2], v1 = va[sub * 2 + 1];
        float partial =
            (u0.x + au[0]) * (v0.x + av[0]) + (u0.y + au[1]) * (v0.y + av[1]) +
            (u0.z + au[2]) * (v0.z + av[2]) + (u0.w + au[3]) * (v0.w + av[3]) +
            (u1.x + au[4]) * (v1.x + av[4]) + (u1.y + au[5]) * (v1.y + av[5]) +
            (u1.z + au[6]) * (v1.z + av[6]) + (u1.w + au[7]) * (v1.w + av[7]);
        partial += __shfl_xor(partial, 1, 64);
        partial += __shfl_xor(partial, 2, 64);
        partial += __shfl_xor(partial, 4, 64);
        if (sub == 0) {
            float g = partial * (1.0f / 16.0f);
            float y = labels[b];
            lb = fmaxf(g, 0.0f) - g * y + log1pf(expf(-fabsf(g)));
        }
    }
    lb += __shfl_xor(lb, 8, 64);
    lb += __shfl_xor(lb, 16, 64);
    lb += __shfl_xor(lb, 32, 64);
    __shared__ float sd[4];
    int wid = threadIdx.x >> 6;
    if ((threadIdx.x & 63) == 0) sd[wid] = lb;
    __syncthreads();
    if (threadIdx.x == 0)
        atomicAdd(out, (sd[0] + sd[1] + sd[2] + sd[3]) / (float)batch);
}

// ---------------------------------------------------------------------------
extern "C" void kernel_launch(void* const* d_in, const int* in_sizes, int n_in,
                              void* d_out, int out_size, void* d_ws, size_t ws_size,
                              hipStream_t stream) {
    const int* users = (const int*)d_in[0];
    const int* items = (const int*)d_in[1];
    const float* labels = (const float*)d_in[2];
    const int* edge_row = (const int*)d_in[3];
    const int* edge_col = (const int*)d_in[4];
    const float* edge_val = (const float*)d_in[5];
    const float* user_emb = (const float*)d_in[6];
    const float* item_emb = (const float*)d_in[7];

    const int batch = in_sizes[0];
    const int n_edges = in_sizes[3];
    const int n_user_rows = in_sizes[6] / D;   // 100001
    const int n_item_rows = in_sizes[7] / D;   // 50000
    const int n_total = n_user_rows + n_item_rows;
    const int nb = (n_total + RB - 1) / RB;          // 293
    const int nblk = (n_edges + CHUNK - 1) / CHUNK;  // 489
    const int L = nb * nblk;                          // 143,277
    const int max_pairs = n_edges + 3 * nb * RB;      // padded upper bound

    auto align256 = [](size_t x) { return (x + 255) & ~(size_t)255; };
    const size_t tblb_bytes = align256((size_t)n_total * D * 2);            // 19.2 MB bf16
    const size_t acc_bytes = align256((size_t)batch * D * sizeof(float));   // 2 MB
    const size_t offs_bytes = align256((size_t)n_total * sizeof(int2));     // 1.2 MB
    const size_t pairs_bytes = align256((size_t)max_pairs * sizeof(int2));  // ~19.6 MB
    const size_t perm_bytes = align256((size_t)n_total * sizeof(int));      // 600 KB
    const size_t hist_bytes = align256((size_t)L * sizeof(int));            // 573 KB
    const size_t cse_bytes = align256((size_t)nb * sizeof(int));

    char* ws = (char*)d_ws;
    unsigned short* tbl  = (unsigned short*)ws;  ws += tblb_bytes;
    unsigned short* buf0 = (unsigned short*)ws;  ws += tblb_bytes;
    unsigned short* buf1 = (unsigned short*)ws;  ws += tblb_bytes;
    float* u_acc  = (float*)ws;                  ws += acc_bytes;
    float* v_acc  = (float*)ws;                  ws += acc_bytes;
    int2*  offs   = (int2*)ws;                   ws += offs_bytes;
    int2*  pairs  = (int2*)ws;                   ws += pairs_bytes;
    int*   perm   = (int*)ws;                    ws += perm_bytes;
    int*   cursor = (int*)ws;                    ws += 1024;   // [0..1]=cursors
    int*   dbin   = cursor + 64;
    int*   dcur   = cursor + 128;
    // stage (16 MB) dead before spmm layer 1 writes buf0 -> alias
    int2*  stage  = (int2*)buf0;
    // CSR-build scratch dead before spmm layer 2 writes buf1 -> alias
    char* sb = (char*)buf1;
    int* hist   = (int*)sb;                      sb += hist_bytes;
    int* cstart = (int*)sb;                      sb += cse_bytes;
    int* cend   = (int*)sb;                      sb += cse_bytes;

    // ---- fused bf16 conversion + per-chunk histogram + zero-init ----
    convhist_kernel<<<nblk, FT, 0, stream>>>(user_emb, item_emb, tbl,
                                             n_user_rows, n_total,
                                             edge_row, hist, n_edges, nb,
                                             cursor, dbin, (float*)d_out);

    // ---- fused column alloc+scan (atomic span allocation per bucket) ----
    const int wave_blocks = (nb + 3) / 4;
    col_alloc_kernel<<<wave_blocks, 256, 0, stream>>>(hist, cstart, cend,
                                                      &cursor[0], nb, nblk);
    fill_exact_kernel<<<nblk, FT, 0, stream>>>(edge_row, edge_col, edge_val,
                                               hist, stage, n_edges, nb);
    bucket_pad_kernel<<<nb, RB, 0, stream>>>(cstart, cend, stage, offs, pairs,
                                             &cursor[1], dbin, n_total);

    // ---- degree-sorted row permutation ----
    scan_bins_kernel<<<1, 64, 0, stream>>>(dbin, dcur);
    perm_fill_kernel<<<(n_total + 255) / 256, 256, 0, stream>>>(offs, dcur, perm, n_total);

    // ---- layers 1,2 full propagation (bf16 gather, f32 accumulate) ----
    const int ga_blocks = (batch * 16 + 255) / 256;
    const int spmm_blocks = (int)(((size_t)n_total * 8 + 255) / 256);
    spmm_gather_kernel<<<spmm_blocks, 256, 0, stream>>>(perm, offs, pairs, tbl, buf0, n_total);
    gather_init_acc_kernel<<<ga_blocks, 256, 0, stream>>>(users, items, user_emb,
                                                          item_emb, buf0, u_acc, v_acc,
                                                          batch, n_user_rows);
    spmm_gather_kernel<<<spmm_blocks, 256, 0, stream>>>(perm, offs, pairs, buf0, buf1, n_total);
    gather_acc_kernel<<<ga_blocks, 256, 0, stream>>>(users, items, buf1,
                                                     u_acc, v_acc, batch, n_user_rows);

    // ---- layer 3 computed ONLY at batch rows, fused with dot + BCE loss ----
    const int bl_blocks = (batch * 8 + 255) / 256;
    batch_l3_loss_kernel<<<bl_blocks, 256, 0, stream>>>(users, items, offs, pairs,
                                                        buf1, u_acc, v_acc, labels,
                                                        (float*)d_out, batch, n_user_rows);
}

// Round 16
// 167.420 us; speedup vs baseline: 1.0924x; 1.0924x over previous
//
#include <hip/hip_runtime.h>
#include <hip/hip_fp16.h>

#define D 64
#define RB 512           // rows per coarse bucket (b = row>>9)
#define RB_SHIFT 9
#define COL_BITS 18      // n_total = 150001 < 2^18; row_local in bits 18..26
#define COL_MASK 0x3FFFF
#define CHUNK 4096       // edges per partition block (489 blocks)
#define FT 512           // threads for hist/fill kernels

// ---------------------------------------------------------------------------
// FUSED: per-chunk bucket histogram + f16 table conversion slice + zero-init
// of cursors/output (block 0; later dispatches see the writes in-stream).
__global__ void convhist_kernel(const float* __restrict__ user_emb,
                                const float* __restrict__ item_emb,
                                __half* __restrict__ tbl,
                                int n_user_rows, int n_total,
                                const int* __restrict__ row,
                                int* __restrict__ hist, int n_edges, int nb,
                                int* __restrict__ cursor,
                                float* __restrict__ out) {
    __shared__ int h[RB];
    int blk = blockIdx.x;
    if (blk == 0) {
        if (threadIdx.x < 2) cursor[threadIdx.x] = 0;
        if (threadIdx.x == 0) out[0] = 0.0f;
    }
    for (int i = threadIdx.x; i < nb; i += FT) h[i] = 0;
    __syncthreads();
    int s = blk * CHUNK;
    int e = min(s + CHUNK, n_edges);
    for (int k = s + threadIdx.x; k < e; k += FT)
        atomicAdd(&h[row[k] >> RB_SHIFT], 1);
    __syncthreads();
    for (int i = threadIdx.x; i < nb; i += FT)
        hist[blk * nb + i] = h[i];   // coalesced row write
    // conversion slice (f32 -> f16)
    size_t t = (size_t)blk * FT + threadIdx.x;
    size_t total4 = (size_t)n_total * (D / 4);
    size_t user4 = (size_t)n_user_rows * (D / 4);
    size_t stride = (size_t)gridDim.x * FT;
    for (size_t i = t; i < total4; i += stride) {
        float4 v = (i < user4) ? reinterpret_cast<const float4*>(user_emb)[i]
                               : reinterpret_cast<const float4*>(item_emb)[i - user4];
        __half2 h01 = __halves2half2(__float2half_rn(v.x), __float2half_rn(v.y));
        __half2 h23 = __halves2half2(__float2half_rn(v.z), __float2half_rn(v.w));
        uint2 o;
        o.x = *reinterpret_cast<unsigned*>(&h01);
        o.y = *reinterpret_cast<unsigned*>(&h23);
        reinterpret_cast<uint2*>(tbl)[i] = o;
    }
}

// ---------------------------------------------------------------------------
// FUSED col_sum + scan + col_scan: ONE WAVE per bucket; atomic span alloc.
__global__ void col_alloc_kernel(int* __restrict__ hist,
                                 int* __restrict__ cstart, int* __restrict__ cend,
                                 int* __restrict__ cursor, int nb, int nblk) {
    int w = (blockIdx.x * blockDim.x + threadIdx.x) >> 6;
    int lane = threadIdx.x & 63;
    if (w >= nb) return;
    int ssum = 0;
    for (int blk = lane; blk < nblk; blk += 64)
        ssum += hist[blk * nb + w];
    for (int off = 32; off > 0; off >>= 1)
        ssum += __shfl_down(ssum, off, 64);
    int base = 0;
    if (lane == 0) base = atomicAdd(cursor, ssum);
    base = __shfl(base, 0, 64);
    int total = __shfl(ssum, 0, 64);
    if (lane == 0) { cstart[w] = base; cend[w] = base + total; }
    int run = base;
    for (int b0 = 0; b0 < nblk; b0 += 64) {
        int blk = b0 + lane;
        int v = (blk < nblk) ? hist[blk * nb + w] : 0;
        int inc = v;
#pragma unroll
        for (int off = 1; off < 64; off <<= 1) {
            int t = __shfl_up(inc, off, 64);
            if (lane >= off) inc += t;
        }
        if (blk < nblk) hist[blk * nb + w] = run + (inc - v);
        run += __shfl(inc, 63, 64);   // chunk total
    }
}

// ---------------------------------------------------------------------------
// Pass C: rank via block-private LDS cursors, write to exact positions
__global__ void fill_exact_kernel(const int* __restrict__ row, const int* __restrict__ col,
                                  const float* __restrict__ val, const int* __restrict__ hist,
                                  int2* __restrict__ stage, int n_edges, int nb) {
    __shared__ int cur[RB];
    int blk = blockIdx.x;
    for (int i = threadIdx.x; i < nb; i += FT)
        cur[i] = hist[blk * nb + i];   // coalesced row read
    __syncthreads();
    int s = blk * CHUNK;
    int e = min(s + CHUNK, n_edges);
    for (int k = s + threadIdx.x; k < e; k += FT) {
        int r = row[k];
        int b = r >> RB_SHIFT;
        int pos = atomicAdd(&cur[b], 1);
        stage[pos] = make_int2(col[k] | ((r & (RB - 1)) << COL_BITS), __float_as_int(val[k]));
    }
}

// ---------------------------------------------------------------------------
// FUSED bucket finalize: row histogram -> padded scan -> atomic span alloc ->
// per-row {start,end} -> pad fill -> row-sorted scatter. Weight stored as
// replicated half2 so spmm needs zero decode ops.
__global__ void bucket_pad_kernel(const int* __restrict__ cstart,
                                  const int* __restrict__ cend,
                                  const int2* __restrict__ stage,
                                  int2* __restrict__ offs,
                                  int2* __restrict__ pairs,
                                  int* __restrict__ cursor, int n_total) {
    __shared__ int sc[RB];
    __shared__ int cur[RB];
    __shared__ int pbase_s;
    int b = blockIdx.x;
    int tid = threadIdx.x;
    int s = cstart[b], e = cend[b];
    sc[tid] = 0;
    __syncthreads();
    for (int k = s + tid; k < e; k += RB)
        atomicAdd(&sc[stage[k].x >> COL_BITS], 1);
    __syncthreads();
    int cnt = sc[tid];
    int pad = (cnt + 3) & ~3;
    __syncthreads();
    sc[tid] = pad;
    __syncthreads();
    for (int off = 1; off < RB; off <<= 1) {
        int v = (tid >= off) ? sc[tid - off] : 0;
        __syncthreads();
        sc[tid] += v;
        __syncthreads();
    }
    if (tid == RB - 1) pbase_s = atomicAdd(cursor, sc[RB - 1]);
    __syncthreads();
    int start = pbase_s + sc[tid] - pad;   // exclusive padded prefix
    int r = b * RB + tid;
    if (r < n_total) offs[r] = make_int2(start, start + pad);
    cur[tid] = start;
    for (int q = start + cnt; q < start + pad; ++q)
        pairs[q] = make_int2(0, 0);   // col 0, weight half2(0,0)
    __syncthreads();
    for (int k = s + tid; k < e; k += RB) {
        int2 p = stage[k];
        int rl = p.x >> COL_BITS;
        int pos = atomicAdd(&cur[rl], 1);
        // encode weight as replicated half2
        __half hw = __float2half_rn(__int_as_float(p.y));
        unsigned hb = (unsigned)*reinterpret_cast<unsigned short*>(&hw);
        pairs[pos] = make_int2(p.x & COL_MASK, (int)(hb | (hb << 16)));
    }
}

// ---------------------------------------------------------------------------
// gather spmm (f16 src/dst, packed-f16 accum via v_pk_fma_f16): ONE 8-LANE
// GROUP PER ROW, tail-free (padded to 4), 8/4 unroll for MLP.
__global__ void spmm_gather_kernel(const int2* __restrict__ offs,
                                   const int2* __restrict__ pairs,
                                   const __half* __restrict__ src,
                                   __half* __restrict__ dst, int n_total) {
    int t = blockIdx.x * blockDim.x + threadIdx.x;
    int r = t >> 3;          // destination row
    int sub = t & 7;         // 16 B slice of the row
    if (r >= n_total) return;
    int2 oo = offs[r];
    int k = oo.x;
    int end = oo.y;
    const uint4* s4 = reinterpret_cast<const uint4*>(src);
    __half2 acc[4];
    acc[0] = __float2half2_rn(0.f);
    acc[1] = acc[0]; acc[2] = acc[0]; acc[3] = acc[0];
    for (; k + 8 <= end; k += 8) {
        int2 p[8];
        uint4 rr[8];
#pragma unroll
        for (int j = 0; j < 8; ++j) p[j] = pairs[k + j];
#pragma unroll
        for (int j = 0; j < 8; ++j) rr[j] = s4[(size_t)p[j].x * 8 + sub];
#pragma unroll
        for (int j = 0; j < 8; ++j) {
            __half2 w2 = *reinterpret_cast<__half2*>(&p[j].y);
            const __half2* rh = reinterpret_cast<const __half2*>(&rr[j]);
            acc[0] = __hfma2(rh[0], w2, acc[0]);
            acc[1] = __hfma2(rh[1], w2, acc[1]);
            acc[2] = __hfma2(rh[2], w2, acc[2]);
            acc[3] = __hfma2(rh[3], w2, acc[3]);
        }
    }
    if (k < end) {   // exactly 4 remain (padded)
        int2 p[4];
        uint4 rr[4];
#pragma unroll
        for (int j = 0; j < 4; ++j) p[j] = pairs[k + j];
#pragma unroll
        for (int j = 0; j < 4; ++j) rr[j] = s4[(size_t)p[j].x * 8 + sub];
#pragma unroll
        for (int j = 0; j < 4; ++j) {
            __half2 w2 = *reinterpret_cast<__half2*>(&p[j].y);
            const __half2* rh = reinterpret_cast<const __half2*>(&rr[j]);
            acc[0] = __hfma2(rh[0], w2, acc[0]);
            acc[1] = __hfma2(rh[1], w2, acc[1]);
            acc[2] = __hfma2(rh[2], w2, acc[2]);
            acc[3] = __hfma2(rh[3], w2, acc[3]);
        }
    }
    reinterpret_cast<uint4*>(dst + (size_t)r * D)[sub] =
        *reinterpret_cast<uint4*>(acc);
}

// ---------------------------------------------------------------------------
// FUSED layers 0+1 batch gather: u_acc = user_emb[u] (f32) + buf0[u] (f16)
__global__ void gather_init_acc_kernel(const int* __restrict__ users,
                                       const int* __restrict__ items,
                                       const float* __restrict__ user_emb,
                                       const float* __restrict__ item_emb,
                                       const __half* __restrict__ buf,
                                       float* __restrict__ u_acc,
                                       float* __restrict__ v_acc,
                                       int batch, int n_user_rows) {
    int t = blockIdx.x * blockDim.x + threadIdx.x;
    int b = t >> 4;
    int sub = t & 15;
    if (b >= batch) return;
    int u = users[b];
    int it = items[b];
    float4 a = reinterpret_cast<const float4*>(user_emb)[(size_t)u * 16 + sub];
    float4 c = reinterpret_cast<const float4*>(item_emb)[(size_t)it * 16 + sub];
    uint2 ur = reinterpret_cast<const uint2*>(buf + (size_t)u * D)[sub];
    uint2 vr = reinterpret_cast<const uint2*>(buf + (size_t)(n_user_rows + it) * D)[sub];
    const __half2* uh = reinterpret_cast<const __half2*>(&ur);
    const __half2* vh = reinterpret_cast<const __half2*>(&vr);
    float2 u0 = __half22float2(uh[0]), u1 = __half22float2(uh[1]);
    float2 v0 = __half22float2(vh[0]), v1 = __half22float2(vh[1]);
    a.x += u0.x; a.y += u0.y; a.z += u1.x; a.w += u1.y;
    c.x += v0.x; c.y += v0.y; c.z += v1.x; c.w += v1.y;
    reinterpret_cast<float4*>(u_acc)[(size_t)b * 16 + sub] = a;
    reinterpret_cast<float4*>(v_acc)[(size_t)b * 16 + sub] = c;
}

// layer 2: accumulate batch rows from f16 buf into f32 acc
__global__ void gather_acc_kernel(const int* __restrict__ users,
                                  const int* __restrict__ items,
                                  const __half* __restrict__ buf,
                                  float* __restrict__ u_acc,
                                  float* __restrict__ v_acc,
                                  int batch, int n_user_rows) {
    int t = blockIdx.x * blockDim.x + threadIdx.x;
    int b = t >> 4;
    int sub = t & 15;
    if (b >= batch) return;
    uint2 ur = reinterpret_cast<const uint2*>(buf + (size_t)users[b] * D)[sub];
    uint2 vr = reinterpret_cast<const uint2*>(buf + (size_t)(n_user_rows + items[b]) * D)[sub];
    const __half2* uh = reinterpret_cast<const __half2*>(&ur);
    const __half2* vh = reinterpret_cast<const __half2*>(&vr);
    float2 u0 = __half22float2(uh[0]), u1 = __half22float2(uh[1]);
    float2 v0 = __half22float2(vh[0]), v1 = __half22float2(vh[1]);
    float4* up = reinterpret_cast<float4*>(u_acc) + (size_t)b * 16 + sub;
    float4* vp = reinterpret_cast<float4*>(v_acc) + (size_t)b * 16 + sub;
    float4 a = *up, c = *vp;
    a.x += u0.x; a.y += u0.y; a.z += u1.x; a.w += u1.y;
    c.x += v0.x; c.y += v0.y; c.z += v1.x; c.w += v1.y;
    *up = a;
    *vp = c;
}

// ---------------------------------------------------------------------------
// Fused final stage: per batch element, compute layer-3 ONLY for its user row
// and item row (4-unrolled, tail-free), add accumulators, dot, BCE, reduce.
__global__ void batch_l3_loss_kernel(const int* __restrict__ users,
                                     const int* __restrict__ items,
                                     const int2* __restrict__ offs,
                                     const int2* __restrict__ pairs,
                                     const __half* __restrict__ buf,
                                     const float* __restrict__ u_acc,
                                     const float* __restrict__ v_acc,
                                     const float* __restrict__ labels,
                                     float* __restrict__ out,
                                     int batch, int n_user_rows) {
    int t = blockIdx.x * blockDim.x + threadIdx.x;
    int b = t >> 3;
    int sub = t & 7;
    const uint4* s4 = reinterpret_cast<const uint4*>(buf);
    float lb = 0.0f;
    if (b < batch) {
        __half2 au[4], av[4];
#pragma unroll
        for (int j = 0; j < 4; ++j) { au[j] = __float2half2_rn(0.f); av[j] = au[j]; }
        for (int side = 0; side < 2; ++side) {
            int row = (side == 0) ? users[b] : (n_user_rows + items[b]);
            __half2* acc = (side == 0) ? au : av;
            int2 oo = offs[row];
            for (int k = oo.x; k + 4 <= oo.y; k += 4) {
                int2 p[4];
                uint4 rr[4];
#pragma unroll
                for (int j = 0; j < 4; ++j) p[j] = pairs[k + j];
#pragma unroll
                for (int j = 0; j < 4; ++j) rr[j] = s4[(size_t)p[j].x * 8 + sub];
#pragma unroll
                for (int j = 0; j < 4; ++j) {
                    __half2 w2 = *reinterpret_cast<__half2*>(&p[j].y);
                    const __half2* rh = reinterpret_cast<const __half2*>(&rr[j]);
                    acc[0] = __hfma2(rh[0], w2, acc[0]);
                    acc[1] = __hfma2(rh[1], w2, acc[1]);
                    acc[2] = __hfma2(rh[2], w2, acc[2]);
                    acc[3] = __hfma2(rh[3], w2, acc[3]);
                }
            }
        }
        const float4* ua = reinterpret_cast<const float4*>(u_acc + (size_t)b * D);
        const float4* va = reinterpret_cast<const float4*>(v_acc + (size_t)b * D);
        float4 u0 = ua[sub * 2], u1 = ua[sub * 2 + 1];
        float4 v0 = va[sub * 2], v1 = va[sub * 2 + 1];
        float2 a0 = __half22float2(au[0]), a1 = __half22float2(au[1]);
        float2 a2 = __half22float2(au[2]), a3 = __half22float2(au[3]);
        float2 c0 = __half22float2(av[0]), c1 = __half22float2(av[1]);
        float2 c2 = __half22float2(av[2]), c3 = __half22float2(av[3]);
        float partial =
            (u0.x + a0.x) * (v0.x + c0.x) + (u0.y + a0.y) * (v0.y + c0.y) +
            (u0.z + a1.x) * (v0.z + c1.x) + (u0.w + a1.y) * (v0.w + c1.y) +
            (u1.x + a2.x) * (v1.x + c2.x) + (u1.y + a2.y) * (v1.y + c2.y) +
            (u1.z + a3.x) * (v1.z + c3.x) + (u1.w + a3.y) * (v1.w + c3.y);
        partial += __shfl_xor(partial, 1, 64);
        partial += __shfl_xor(partial, 2, 64);
        partial += __shfl_xor(partial, 4, 64);
        if (sub == 0) {
            float g = partial * (1.0f / 16.0f);
            float y = labels[b];
            lb = fmaxf(g, 0.0f) - g * y + log1pf(expf(-fabsf(g)));
        }
    }
    lb += __shfl_xor(lb, 8, 64);
    lb += __shfl_xor(lb, 16, 64);
    lb += __shfl_xor(lb, 32, 64);
    __shared__ float sd[4];
    int wid = threadIdx.x >> 6;
    if ((threadIdx.x & 63) == 0) sd[wid] = lb;
    __syncthreads();
    if (threadIdx.x == 0)
        atomicAdd(out, (sd[0] + sd[1] + sd[2] + sd[3]) / (float)batch);
}

// ---------------------------------------------------------------------------
extern "C" void kernel_launch(void* const* d_in, const int* in_sizes, int n_in,
                              void* d_out, int out_size, void* d_ws, size_t ws_size,
                              hipStream_t stream) {
    const int* users = (const int*)d_in[0];
    const int* items = (const int*)d_in[1];
    const float* labels = (const float*)d_in[2];
    const int* edge_row = (const int*)d_in[3];
    const int* edge_col = (const int*)d_in[4];
    const float* edge_val = (const float*)d_in[5];
    const float* user_emb = (const float*)d_in[6];
    const float* item_emb = (const float*)d_in[7];

    const int batch = in_sizes[0];
    const int n_edges = in_sizes[3];
    const int n_user_rows = in_sizes[6] / D;   // 100001
    const int n_item_rows = in_sizes[7] / D;   // 50000
    const int n_total = n_user_rows + n_item_rows;
    const int nb = (n_total + RB - 1) / RB;          // 293
    const int nblk = (n_edges + CHUNK - 1) / CHUNK;  // 489
    const int L = nb * nblk;                          // 143,277
    const int max_pairs = n_edges + 3 * nb * RB;      // padded upper bound

    auto align256 = [](size_t x) { return (x + 255) & ~(size_t)255; };
    const size_t tblb_bytes = align256((size_t)n_total * D * 2);            // 19.2 MB f16
    const size_t acc_bytes = align256((size_t)batch * D * sizeof(float));   // 2 MB
    const size_t offs_bytes = align256((size_t)n_total * sizeof(int2));     // 1.2 MB
    const size_t pairs_bytes = align256((size_t)max_pairs * sizeof(int2));  // ~19.6 MB
    const size_t hist_bytes = align256((size_t)L * sizeof(int));            // 573 KB
    const size_t cse_bytes = align256((size_t)nb * sizeof(int));

    char* ws = (char*)d_ws;
    __half* tbl  = (__half*)ws;                  ws += tblb_bytes;
    __half* buf0 = (__half*)ws;                  ws += tblb_bytes;
    __half* buf1 = (__half*)ws;                  ws += tblb_bytes;
    float* u_acc  = (float*)ws;                  ws += acc_bytes;
    float* v_acc  = (float*)ws;                  ws += acc_bytes;
    int2*  offs   = (int2*)ws;                   ws += offs_bytes;
    int2*  pairs  = (int2*)ws;                   ws += pairs_bytes;
    int*   cursor = (int*)ws;                    ws += 256;
    // stage (16 MB) dead before spmm layer 1 writes buf0 -> alias
    int2*  stage  = (int2*)buf0;
    // CSR-build scratch dead before spmm layer 2 writes buf1 -> alias
    char* sb = (char*)buf1;
    int* hist   = (int*)sb;                      sb += hist_bytes;
    int* cstart = (int*)sb;                      sb += cse_bytes;
    int* cend   = (int*)sb;                      sb += cse_bytes;

    // ---- fused f16 conversion + per-chunk histogram + zero-init ----
    convhist_kernel<<<nblk, FT, 0, stream>>>(user_emb, item_emb, tbl,
                                             n_user_rows, n_total,
                                             edge_row, hist, n_edges, nb,
                                             cursor, (float*)d_out);

    // ---- fused column alloc+scan (atomic span allocation per bucket) ----
    const int wave_blocks = (nb + 3) / 4;
    col_alloc_kernel<<<wave_blocks, 256, 0, stream>>>(hist, cstart, cend,
                                                      &cursor[0], nb, nblk);
    fill_exact_kernel<<<nblk, FT, 0, stream>>>(edge_row, edge_col, edge_val,
                                               hist, stage, n_edges, nb);
    bucket_pad_kernel<<<nb, RB, 0, stream>>>(cstart, cend, stage, offs, pairs,
                                             &cursor[1], n_total);

    // ---- layers 1,2 full propagation (f16 gather, packed-f16 accumulate) ----
    const int ga_blocks = (batch * 16 + 255) / 256;
    const int spmm_blocks = (int)(((size_t)n_total * 8 + 255) / 256);
    spmm_gather_kernel<<<spmm_blocks, 256, 0, stream>>>(offs, pairs, tbl, buf0, n_total);
    gather_init_acc_kernel<<<ga_blocks, 256, 0, stream>>>(users, items, user_emb,
                                                          item_emb, buf0, u_acc, v_acc,
                                                          batch, n_user_rows);
    spmm_gather_kernel<<<spmm_blocks, 256, 0, stream>>>(offs, pairs, buf0, buf1, n_total);
    gather_acc_kernel<<<ga_blocks, 256, 0, stream>>>(users, items, buf1,
                                                     u_acc, v_acc, batch, n_user_rows);

    // ---- layer 3 computed ONLY at batch rows, fused with dot + BCE loss ----
    const int bl_blocks = (batch * 8 + 255) / 256;
    batch_l3_loss_kernel<<<bl_blocks, 256, 0, stream>>>(users, items, offs, pairs,
                                                        buf1, u_acc, v_acc, labels,
                                                        (float*)d_out, batch, n_user_rows);
}

// Round 17
// 164.935 us; speedup vs baseline: 1.1089x; 1.0151x over previous
//
#include <hip/hip_runtime.h>
#include <hip/hip_fp16.h>

#define D 64
#define RB 512           // rows per coarse bucket (b = row>>9)
#define RB_SHIFT 9
#define COL_BITS 18      // n_total = 150001 < 2^18; row_local in bits 18..26
#define COL_MASK 0x3FFFF
#define CHUNK 4096       // edges per partition block (489 blocks)
#define FT 512           // threads for hist/fill kernels

// ---------------------------------------------------------------------------
// FUSED: per-chunk bucket histogram + f16 table conversion slice + zero-init
// of cursors/output (block 0; later dispatches see the writes in-stream).
__global__ void convhist_kernel(const float* __restrict__ user_emb,
                                const float* __restrict__ item_emb,
                                __half* __restrict__ tbl,
                                int n_user_rows, int n_total,
                                const int* __restrict__ row,
                                int* __restrict__ hist, int n_edges, int nb,
                                int* __restrict__ cursor,
                                float* __restrict__ out) {
    __shared__ int h[RB];
    int blk = blockIdx.x;
    if (blk == 0) {
        if (threadIdx.x < 2) cursor[threadIdx.x] = 0;
        if (threadIdx.x == 0) out[0] = 0.0f;
    }
    for (int i = threadIdx.x; i < nb; i += FT) h[i] = 0;
    __syncthreads();
    int s = blk * CHUNK;
    int e = min(s + CHUNK, n_edges);
    for (int k = s + threadIdx.x; k < e; k += FT)
        atomicAdd(&h[row[k] >> RB_SHIFT], 1);
    __syncthreads();
    for (int i = threadIdx.x; i < nb; i += FT)
        hist[blk * nb + i] = h[i];   // coalesced row write
    // conversion slice (f32 -> f16)
    size_t t = (size_t)blk * FT + threadIdx.x;
    size_t total4 = (size_t)n_total * (D / 4);
    size_t user4 = (size_t)n_user_rows * (D / 4);
    size_t stride = (size_t)gridDim.x * FT;
    for (size_t i = t; i < total4; i += stride) {
        float4 v = (i < user4) ? reinterpret_cast<const float4*>(user_emb)[i]
                               : reinterpret_cast<const float4*>(item_emb)[i - user4];
        __half2 h01 = __halves2half2(__float2half_rn(v.x), __float2half_rn(v.y));
        __half2 h23 = __halves2half2(__float2half_rn(v.z), __float2half_rn(v.w));
        uint2 o;
        o.x = *reinterpret_cast<unsigned*>(&h01);
        o.y = *reinterpret_cast<unsigned*>(&h23);
        reinterpret_cast<uint2*>(tbl)[i] = o;
    }
}

// ---------------------------------------------------------------------------
// FUSED col_sum + scan + col_scan: ONE WAVE per bucket; atomic span alloc.
__global__ void col_alloc_kernel(int* __restrict__ hist,
                                 int* __restrict__ cstart, int* __restrict__ cend,
                                 int* __restrict__ cursor, int nb, int nblk) {
    int w = (blockIdx.x * blockDim.x + threadIdx.x) >> 6;
    int lane = threadIdx.x & 63;
    if (w >= nb) return;
    int ssum = 0;
    for (int blk = lane; blk < nblk; blk += 64)
        ssum += hist[blk * nb + w];
    for (int off = 32; off > 0; off >>= 1)
        ssum += __shfl_down(ssum, off, 64);
    int base = 0;
    if (lane == 0) base = atomicAdd(cursor, ssum);
    base = __shfl(base, 0, 64);
    int run = base;
    int total = __shfl(ssum, 0, 64);
    if (lane == 0) { cstart[w] = base; cend[w] = base + total; }
    for (int b0 = 0; b0 < nblk; b0 += 64) {
        int blk = b0 + lane;
        int v = (blk < nblk) ? hist[blk * nb + w] : 0;
        int inc = v;
#pragma unroll
        for (int off = 1; off < 64; off <<= 1) {
            int t = __shfl_up(inc, off, 64);
            if (lane >= off) inc += t;
        }
        if (blk < nblk) hist[blk * nb + w] = run + (inc - v);
        run += __shfl(inc, 63, 64);   // chunk total
    }
}

// ---------------------------------------------------------------------------
// Pass C: LDS-sorted fill. Rank edges via LDS histogram atomic returns,
// shuffle-scan the bucket counts, place (data, global addr) into LDS in
// bucket-sorted order, then drain with coalesced run writes.
__global__ void fill_exact_kernel(const int* __restrict__ row, const int* __restrict__ col,
                                  const float* __restrict__ val, const int* __restrict__ hist,
                                  int2* __restrict__ stage, int n_edges, int nb) {
    __shared__ int hloc[RB];
    __shared__ int lbase[RB];
    __shared__ int gbase[RB];
    __shared__ int wsum[FT / 64];
    __shared__ int2 sdata[CHUNK];   // 32 KB
    __shared__ int  saddr[CHUNK];   // 16 KB
    int blk = blockIdx.x;
    int tid = threadIdx.x;
    int lane = tid & 63, wid = tid >> 6;
    for (int i = tid; i < nb; i += FT) {
        hloc[i] = 0;
        gbase[i] = hist[blk * nb + i];
    }
    __syncthreads();
    int s = blk * CHUNK;
    int e = min(s + CHUNK, n_edges);
    int cnt = e - s;
    int2 data[8];
    int bkt[8], rnk[8];
    int nloc = 0;
#pragma unroll
    for (int j = 0; j < 8; ++j) {
        int k = s + j * FT + tid;
        if (k < e) {
            int r = row[k];
            int b = r >> RB_SHIFT;
            data[nloc] = make_int2(col[k] | ((r & (RB - 1)) << COL_BITS),
                                   __float_as_int(val[k]));
            bkt[nloc] = b;
            rnk[nloc] = atomicAdd(&hloc[b], 1);
            ++nloc;
        }
    }
    __syncthreads();
    // exclusive scan of hloc[0..nb) -> lbase (shfl + cross-wave)
    int v = (tid < nb) ? hloc[tid] : 0;
    int inc = v;
#pragma unroll
    for (int off = 1; off < 64; off <<= 1) {
        int t = __shfl_up(inc, off, 64);
        if (lane >= off) inc += t;
    }
    if (lane == 63) wsum[wid] = inc;
    __syncthreads();
    if (wid == 0) {
        int wv = (lane < FT / 64) ? wsum[lane] : 0;
        int wi = wv;
#pragma unroll
        for (int off = 1; off < FT / 64; off <<= 1) {
            int t = __shfl_up(wi, off, 64);
            if (lane >= off) wi += t;
        }
        if (lane < FT / 64) wsum[lane] = wi - wv;   // exclusive
    }
    __syncthreads();
    if (tid < nb) lbase[tid] = (inc - v) + wsum[wid];
    __syncthreads();
    // place into LDS sorted order with precomputed global addresses
    for (int j = 0; j < nloc; ++j) {
        int b = bkt[j];
        int pos = lbase[b] + rnk[j];
        sdata[pos] = data[j];
        saddr[pos] = gbase[b] + rnk[j];
    }
    __syncthreads();
    // drain: consecutive threads -> consecutive addresses within runs
    for (int j = tid; j < cnt; j += FT)
        stage[saddr[j]] = sdata[j];
}

// ---------------------------------------------------------------------------
// FUSED bucket finalize: row histogram -> padded shfl-scan -> atomic span
// alloc -> per-row {start,end} -> pad fill -> row-sorted scatter. Weight
// stored as replicated half2 so spmm needs zero decode ops.
__global__ void bucket_pad_kernel(const int* __restrict__ cstart,
                                  const int* __restrict__ cend,
                                  const int2* __restrict__ stage,
                                  int2* __restrict__ offs,
                                  int2* __restrict__ pairs,
                                  int* __restrict__ cursor, int n_total) {
    __shared__ int sc[RB];
    __shared__ int cur[RB];
    __shared__ int wsum[RB / 64];
    __shared__ int pbase_s;
    int b = blockIdx.x;
    int tid = threadIdx.x;
    int lane = tid & 63, wid = tid >> 6;
    int s = cstart[b], e = cend[b];
    sc[tid] = 0;
    __syncthreads();
    for (int k = s + tid; k < e; k += RB)
        atomicAdd(&sc[stage[k].x >> COL_BITS], 1);
    __syncthreads();
    int cnt = sc[tid];
    int pad = (cnt + 3) & ~3;
    // inclusive shfl scan of pad over 512 threads
    int inc = pad;
#pragma unroll
    for (int off = 1; off < 64; off <<= 1) {
        int t = __shfl_up(inc, off, 64);
        if (lane >= off) inc += t;
    }
    if (lane == 63) wsum[wid] = inc;
    __syncthreads();
    if (wid == 0) {
        int wv = (lane < RB / 64) ? wsum[lane] : 0;
        int wi = wv;
#pragma unroll
        for (int off = 1; off < RB / 64; off <<= 1) {
            int t = __shfl_up(wi, off, 64);
            if (lane >= off) wi += t;
        }
        if (lane < RB / 64) wsum[lane] = wi - wv;   // exclusive
    }
    __syncthreads();
    int incl = inc + wsum[wid];
    if (tid == RB - 1) pbase_s = atomicAdd(cursor, incl);
    __syncthreads();
    int start = pbase_s + incl - pad;   // exclusive padded prefix
    int r = b * RB + tid;
    if (r < n_total) offs[r] = make_int2(start, start + pad);
    cur[tid] = start;
    for (int q = start + cnt; q < start + pad; ++q)
        pairs[q] = make_int2(0, 0);   // col 0, weight half2(0,0)
    __syncthreads();
    for (int k = s + tid; k < e; k += RB) {
        int2 p = stage[k];
        int rl = p.x >> COL_BITS;
        int pos = atomicAdd(&cur[rl], 1);
        __half hw = __float2half_rn(__int_as_float(p.y));
        unsigned hb = (unsigned)*reinterpret_cast<unsigned short*>(&hw);
        pairs[pos] = make_int2(p.x & COL_MASK, (int)(hb | (hb << 16)));
    }
}

// ---------------------------------------------------------------------------
// gather spmm (f16 src/dst, packed-f16 accum via v_pk_fma_f16): ONE 8-LANE
// GROUP PER ROW, tail-free (padded to 4), 8/4 unroll, uint4 pair loads.
__global__ void spmm_gather_kernel(const int2* __restrict__ offs,
                                   const int2* __restrict__ pairs,
                                   const __half* __restrict__ src,
                                   __half* __restrict__ dst, int n_total) {
    int t = blockIdx.x * blockDim.x + threadIdx.x;
    int r = t >> 3;          // destination row
    int sub = t & 7;         // 16 B slice of the row
    if (r >= n_total) return;
    int2 oo = offs[r];
    int k = oo.x;
    int end = oo.y;
    const uint4* s4 = reinterpret_cast<const uint4*>(src);
    __half2 acc[4];
    acc[0] = __float2half2_rn(0.f);
    acc[1] = acc[0]; acc[2] = acc[0]; acc[3] = acc[0];
    for (; k + 8 <= end; k += 8) {
        uint4 q[4];
#pragma unroll
        for (int j = 0; j < 4; ++j)
            q[j] = reinterpret_cast<const uint4*>(pairs + k)[j];
        uint4 rr[8];
#pragma unroll
        for (int j = 0; j < 4; ++j) {
            rr[2 * j]     = s4[(size_t)q[j].x * 8 + sub];
            rr[2 * j + 1] = s4[(size_t)q[j].z * 8 + sub];
        }
#pragma unroll
        for (int j = 0; j < 4; ++j) {
            __half2 w0 = *reinterpret_cast<__half2*>(&q[j].y);
            __half2 w1 = *reinterpret_cast<__half2*>(&q[j].w);
            const __half2* r0 = reinterpret_cast<const __half2*>(&rr[2 * j]);
            const __half2* r1 = reinterpret_cast<const __half2*>(&rr[2 * j + 1]);
            acc[0] = __hfma2(r0[0], w0, acc[0]);
            acc[1] = __hfma2(r0[1], w0, acc[1]);
            acc[2] = __hfma2(r0[2], w0, acc[2]);
            acc[3] = __hfma2(r0[3], w0, acc[3]);
            acc[0] = __hfma2(r1[0], w1, acc[0]);
            acc[1] = __hfma2(r1[1], w1, acc[1]);
            acc[2] = __hfma2(r1[2], w1, acc[2]);
            acc[3] = __hfma2(r1[3], w1, acc[3]);
        }
    }
    if (k < end) {   // exactly 4 remain (padded)
        uint4 q[2];
        q[0] = reinterpret_cast<const uint4*>(pairs + k)[0];
        q[1] = reinterpret_cast<const uint4*>(pairs + k)[1];
        uint4 rr[4];
#pragma unroll
        for (int j = 0; j < 2; ++j) {
            rr[2 * j]     = s4[(size_t)q[j].x * 8 + sub];
            rr[2 * j + 1] = s4[(size_t)q[j].z * 8 + sub];
        }
#pragma unroll
        for (int j = 0; j < 2; ++j) {
            __half2 w0 = *reinterpret_cast<__half2*>(&q[j].y);
            __half2 w1 = *reinterpret_cast<__half2*>(&q[j].w);
            const __half2* r0 = reinterpret_cast<const __half2*>(&rr[2 * j]);
            const __half2* r1 = reinterpret_cast<const __half2*>(&rr[2 * j + 1]);
            acc[0] = __hfma2(r0[0], w0, acc[0]);
            acc[1] = __hfma2(r0[1], w0, acc[1]);
            acc[2] = __hfma2(r0[2], w0, acc[2]);
            acc[3] = __hfma2(r0[3], w0, acc[3]);
            acc[0] = __hfma2(r1[0], w1, acc[0]);
            acc[1] = __hfma2(r1[1], w1, acc[1]);
            acc[2] = __hfma2(r1[2], w1, acc[2]);
            acc[3] = __hfma2(r1[3], w1, acc[3]);
        }
    }
    reinterpret_cast<uint4*>(dst + (size_t)r * D)[sub] =
        *reinterpret_cast<uint4*>(acc);
}

// ---------------------------------------------------------------------------
// FUSED layers 0+1 batch gather: u_acc = user_emb[u] (f32) + buf0[u] (f16)
__global__ void gather_init_acc_kernel(const int* __restrict__ users,
                                       const int* __restrict__ items,
                                       const float* __restrict__ user_emb,
                                       const float* __restrict__ item_emb,
                                       const __half* __restrict__ buf,
                                       float* __restrict__ u_acc,
                                       float* __restrict__ v_acc,
                                       int batch, int n_user_rows) {
    int t = blockIdx.x * blockDim.x + threadIdx.x;
    int b = t >> 4;
    int sub = t & 15;
    if (b >= batch) return;
    int u = users[b];
    int it = items[b];
    float4 a = reinterpret_cast<const float4*>(user_emb)[(size_t)u * 16 + sub];
    float4 c = reinterpret_cast<const float4*>(item_emb)[(size_t)it * 16 + sub];
    uint2 ur = reinterpret_cast<const uint2*>(buf + (size_t)u * D)[sub];
    uint2 vr = reinterpret_cast<const uint2*>(buf + (size_t)(n_user_rows + it) * D)[sub];
    const __half2* uh = reinterpret_cast<const __half2*>(&ur);
    const __half2* vh = reinterpret_cast<const __half2*>(&vr);
    float2 u0 = __half22float2(uh[0]), u1 = __half22float2(uh[1]);
    float2 v0 = __half22float2(vh[0]), v1 = __half22float2(vh[1]);
    a.x += u0.x; a.y += u0.y; a.z += u1.x; a.w += u1.y;
    c.x += v0.x; c.y += v0.y; c.z += v1.x; c.w += v1.y;
    reinterpret_cast<float4*>(u_acc)[(size_t)b * 16 + sub] = a;
    reinterpret_cast<float4*>(v_acc)[(size_t)b * 16 + sub] = c;
}

// layer 2: accumulate batch rows from f16 buf into f32 acc
__global__ void gather_acc_kernel(const int* __restrict__ users,
                                  const int* __restrict__ items,
                                  const __half* __restrict__ buf,
                                  float* __restrict__ u_acc,
                                  float* __restrict__ v_acc,
                                  int batch, int n_user_rows) {
    int t = blockIdx.x * blockDim.x + threadIdx.x;
    int b = t >> 4;
    int sub = t & 15;
    if (b >= batch) return;
    uint2 ur = reinterpret_cast<const uint2*>(buf + (size_t)users[b] * D)[sub];
    uint2 vr = reinterpret_cast<const uint2*>(buf + (size_t)(n_user_rows + items[b]) * D)[sub];
    const __half2* uh = reinterpret_cast<const __half2*>(&ur);
    const __half2* vh = reinterpret_cast<const __half2*>(&vr);
    float2 u0 = __half22float2(uh[0]), u1 = __half22float2(uh[1]);
    float2 v0 = __half22float2(vh[0]), v1 = __half22float2(vh[1]);
    float4* up = reinterpret_cast<float4*>(u_acc) + (size_t)b * 16 + sub;
    float4* vp = reinterpret_cast<float4*>(v_acc) + (size_t)b * 16 + sub;
    float4 a = *up, c = *vp;
    a.x += u0.x; a.y += u0.y; a.z += u1.x; a.w += u1.y;
    c.x += v0.x; c.y += v0.y; c.z += v1.x; c.w += v1.y;
    *up = a;
    *vp = c;
}

// ---------------------------------------------------------------------------
// Fused final stage: per batch element, compute layer-3 ONLY for its user row
// and item row (4-unrolled, tail-free), add accumulators, dot, BCE, reduce.
__global__ void batch_l3_loss_kernel(const int* __restrict__ users,
                                     const int* __restrict__ items,
                                     const int2* __restrict__ offs,
                                     const int2* __restrict__ pairs,
                                     const __half* __restrict__ buf,
                                     const float* __restrict__ u_acc,
                                     const float* __restrict__ v_acc,
                                     const float* __restrict__ labels,
                                     float* __restrict__ out,
                                     int batch, int n_user_rows) {
    int t = blockIdx.x * blockDim.x + threadIdx.x;
    int b = t >> 3;
    int sub = t & 7;
    const uint4* s4 = reinterpret_cast<const uint4*>(buf);
    float lb = 0.0f;
    if (b < batch) {
        __half2 au[4], av[4];
#pragma unroll
        for (int j = 0; j < 4; ++j) { au[j] = __float2half2_rn(0.f); av[j] = au[j]; }
        for (int side = 0; side < 2; ++side) {
            int row = (side == 0) ? users[b] : (n_user_rows + items[b]);
            __half2* acc = (side == 0) ? au : av;
            int2 oo = offs[row];
            for (int k = oo.x; k + 4 <= oo.y; k += 4) {
                uint4 q[2];
                q[0] = reinterpret_cast<const uint4*>(pairs + k)[0];
                q[1] = reinterpret_cast<const uint4*>(pairs + k)[1];
                uint4 rr[4];
#pragma unroll
                for (int j = 0; j < 2; ++j) {
                    rr[2 * j]     = s4[(size_t)q[j].x * 8 + sub];
                    rr[2 * j + 1] = s4[(size_t)q[j].z * 8 + sub];
                }
#pragma unroll
                for (int j = 0; j < 2; ++j) {
                    __half2 w0 = *reinterpret_cast<__half2*>(&q[j].y);
                    __half2 w1 = *reinterpret_cast<__half2*>(&q[j].w);
                    const __half2* r0 = reinterpret_cast<const __half2*>(&rr[2 * j]);
                    const __half2* r1 = reinterpret_cast<const __half2*>(&rr[2 * j + 1]);
                    acc[0] = __hfma2(r0[0], w0, acc[0]);
                    acc[1] = __hfma2(r0[1], w0, acc[1]);
                    acc[2] = __hfma2(r0[2], w0, acc[2]);
                    acc[3] = __hfma2(r0[3], w0, acc[3]);
                    acc[0] = __hfma2(r1[0], w1, acc[0]);
                    acc[1] = __hfma2(r1[1], w1, acc[1]);
                    acc[2] = __hfma2(r1[2], w1, acc[2]);
                    acc[3] = __hfma2(r1[3], w1, acc[3]);
                }
            }
        }
        const float4* ua = reinterpret_cast<const float4*>(u_acc + (size_t)b * D);
        const float4* va = reinterpret_cast<const float4*>(v_acc + (size_t)b * D);
        float4 u0 = ua[sub * 2], u1 = ua[sub * 2 + 1];
        float4 v0 = va[sub * 2], v1 = va[sub * 2 + 1];
        float2 a0 = __half22float2(au[0]), a1 = __half22float2(au[1]);
        float2 a2 = __half22float2(au[2]), a3 = __half22float2(au[3]);
        float2 c0 = __half22float2(av[0]), c1 = __half22float2(av[1]);
        float2 c2 = __half22float2(av[2]), c3 = __half22float2(av[3]);
        float partial =
            (u0.x + a0.x) * (v0.x + c0.x) + (u0.y + a0.y) * (v0.y + c0.y) +
            (u0.z + a1.x) * (v0.z + c1.x) + (u0.w + a1.y) * (v0.w + c1.y) +
            (u1.x + a2.x) * (v1.x + c2.x) + (u1.y + a2.y) * (v1.y + c2.y) +
            (u1.z + a3.x) * (v1.z + c3.x) + (u1.w + a3.y) * (v1.w + c3.y);
        partial += __shfl_xor(partial, 1, 64);
        partial += __shfl_xor(partial, 2, 64);
        partial += __shfl_xor(partial, 4, 64);
        if (sub == 0) {
            float g = partial * (1.0f / 16.0f);
            float y = labels[b];
            lb = fmaxf(g, 0.0f) - g * y + log1pf(expf(-fabsf(g)));
        }
    }
    lb += __shfl_xor(lb, 8, 64);
    lb += __shfl_xor(lb, 16, 64);
    lb += __shfl_xor(lb, 32, 64);
    __shared__ float sd[4];
    int wid = threadIdx.x >> 6;
    if ((threadIdx.x & 63) == 0) sd[wid] = lb;
    __syncthreads();
    if (threadIdx.x == 0)
        atomicAdd(out, (sd[0] + sd[1] + sd[2] + sd[3]) / (float)batch);
}

// ---------------------------------------------------------------------------
extern "C" void kernel_launch(void* const* d_in, const int* in_sizes, int n_in,
                              void* d_out, int out_size, void* d_ws, size_t ws_size,
                              hipStream_t stream) {
    const int* users = (const int*)d_in[0];
    const int* items = (const int*)d_in[1];
    const float* labels = (const float*)d_in[2];
    const int* edge_row = (const int*)d_in[3];
    const int* edge_col = (const int*)d_in[4];
    const float* edge_val = (const float*)d_in[5];
    const float* user_emb = (const float*)d_in[6];
    const float* item_emb = (const float*)d_in[7];

    const int batch = in_sizes[0];
    const int n_edges = in_sizes[3];
    const int n_user_rows = in_sizes[6] / D;   // 100001
    const int n_item_rows = in_sizes[7] / D;   // 50000
    const int n_total = n_user_rows + n_item_rows;
    const int nb = (n_total + RB - 1) / RB;          // 293
    const int nblk = (n_edges + CHUNK - 1) / CHUNK;  // 489
    const int L = nb * nblk;                          // 143,277
    const int max_pairs = n_edges + 3 * nb * RB;      // padded upper bound

    auto align256 = [](size_t x) { return (x + 255) & ~(size_t)255; };
    const size_t tblb_bytes = align256((size_t)n_total * D * 2);            // 19.2 MB f16
    const size_t acc_bytes = align256((size_t)batch * D * sizeof(float));   // 2 MB
    const size_t offs_bytes = align256((size_t)n_total * sizeof(int2));     // 1.2 MB
    const size_t pairs_bytes = align256((size_t)max_pairs * sizeof(int2));  // ~19.6 MB
    const size_t hist_bytes = align256((size_t)L * sizeof(int));            // 573 KB
    const size_t cse_bytes = align256((size_t)nb * sizeof(int));

    char* ws = (char*)d_ws;
    __half* tbl  = (__half*)ws;                  ws += tblb_bytes;
    __half* buf0 = (__half*)ws;                  ws += tblb_bytes;
    __half* buf1 = (__half*)ws;                  ws += tblb_bytes;
    float* u_acc  = (float*)ws;                  ws += acc_bytes;
    float* v_acc  = (float*)ws;                  ws += acc_bytes;
    int2*  offs   = (int2*)ws;                   ws += offs_bytes;
    int2*  pairs  = (int2*)ws;                   ws += pairs_bytes;
    int*   cursor = (int*)ws;                    ws += 256;
    // stage (16 MB) dead before spmm layer 1 writes buf0 -> alias
    int2*  stage  = (int2*)buf0;
    // CSR-build scratch dead before spmm layer 2 writes buf1 -> alias
    char* sb = (char*)buf1;
    int* hist   = (int*)sb;                      sb += hist_bytes;
    int* cstart = (int*)sb;                      sb += cse_bytes;
    int* cend   = (int*)sb;                      sb += cse_bytes;

    // ---- fused f16 conversion + per-chunk histogram + zero-init ----
    convhist_kernel<<<nblk, FT, 0, stream>>>(user_emb, item_emb, tbl,
                                             n_user_rows, n_total,
                                             edge_row, hist, n_edges, nb,
                                             cursor, (float*)d_out);

    // ---- fused column alloc+scan (atomic span allocation per bucket) ----
    const int wave_blocks = (nb + 3) / 4;
    col_alloc_kernel<<<wave_blocks, 256, 0, stream>>>(hist, cstart, cend,
                                                      &cursor[0], nb, nblk);
    fill_exact_kernel<<<nblk, FT, 0, stream>>>(edge_row, edge_col, edge_val,
                                               hist, stage, n_edges, nb);
    bucket_pad_kernel<<<nb, RB, 0, stream>>>(cstart, cend, stage, offs, pairs,
                                             &cursor[1], n_total);

    // ---- layers 1,2 full propagation (f16 gather, packed-f16 accumulate) ----
    const int ga_blocks = (batch * 16 + 255) / 256;
    const int spmm_blocks = (int)(((size_t)n_total * 8 + 255) / 256);
    spmm_gather_kernel<<<spmm_blocks, 256, 0, stream>>>(offs, pairs, tbl, buf0, n_total);
    gather_init_acc_kernel<<<ga_blocks, 256, 0, stream>>>(users, items, user_emb,
                                                          item_emb, buf0, u_acc, v_acc,
                                                          batch, n_user_rows);
    spmm_gather_kernel<<<spmm_blocks, 256, 0, stream>>>(offs, pairs, buf0, buf1, n_total);
    gather_acc_kernel<<<ga_blocks, 256, 0, stream>>>(users, items, buf1,
                                                     u_acc, v_acc, batch, n_user_rows);

    // ---- layer 3 computed ONLY at batch rows, fused with dot + BCE loss ----
    const int bl_blocks = (batch * 8 + 255) / 256;
    batch_l3_loss_kernel<<<bl_blocks, 256, 0, stream>>>(users, items, offs, pairs,
                                                        buf1, u_acc, v_acc, labels,
                                                        (float*)d_out, batch, n_user_rows);
}